// Round 1
// baseline (523.719 us; speedup 1.0000x reference)
//
#include <hip/hip_runtime.h>
#include <hip/hip_bf16.h>

#define BB   4096
#define DD   128
#define NII  50000

typedef __attribute__((ext_vector_type(8))) short  bf8_t;   // 8 bf16 in 4 VGPRs
typedef __attribute__((ext_vector_type(4))) float  f4_t;
typedef __attribute__((ext_vector_type(4))) unsigned short us4_t;
typedef __attribute__((ext_vector_type(4))) float  fl4_t;

static __device__ __forceinline__ unsigned short f2bf(float f) {
    unsigned u = __float_as_uint(f);
    u += 0x7fffu + ((u >> 16) & 1u);       // round-to-nearest-even
    return (unsigned short)(u >> 16);
}

// ---------------- K1: gather + LN1 + t = nf @ send_W, s2 = t . a2 ----------------
__global__ __launch_bounds__(128) void k1_embed_send(
    const int* __restrict__ uidx, const float* __restrict__ utab,
    const float* __restrict__ g1, const float* __restrict__ b1,
    const float* __restrict__ sendW, const float* __restrict__ senda,
    float* __restrict__ t_out, float* __restrict__ s2_out)
{
    __shared__ float sb[128];
    __shared__ float nf[128];
    const int row = blockIdx.x;
    const int tid = threadIdx.x;
    const long urow = uidx[row];
    const float x = utab[urow * 128 + tid];

    sb[tid] = x; __syncthreads();
    for (int s = 64; s > 0; s >>= 1) { if (tid < s) sb[tid] += sb[tid + s]; __syncthreads(); }
    const float mean = sb[0] * (1.0f / 128.0f); __syncthreads();
    const float dv = x - mean;
    sb[tid] = dv * dv; __syncthreads();
    for (int s = 64; s > 0; s >>= 1) { if (tid < s) sb[tid] += sb[tid + s]; __syncthreads(); }
    const float var = sb[0] * (1.0f / 128.0f);
    const float rs = rsqrtf(var + 1e-5f);
    nf[tid] = dv * rs * g1[tid] + b1[tid];
    __syncthreads();

    float acc = 0.f;
    #pragma unroll 8
    for (int d = 0; d < 128; ++d) acc += nf[d] * sendW[d * 128 + tid];
    t_out[row * 128 + tid] = acc;

    const float p = acc * senda[128 + tid];   // a2 = send_a[128:]
    __syncthreads();
    sb[tid] = p; __syncthreads();
    for (int s = 64; s > 0; s >>= 1) { if (tid < s) sb[tid] += sb[tid + s]; __syncthreads(); }
    if (tid == 0) s2_out[row] = sb[0];
}

// ---------------- K2a: m = max(s2), S = sum exp(s2-m) ----------------
__global__ __launch_bounds__(256) void k2a_stats(
    const float* __restrict__ s2, float* __restrict__ red)
{
    __shared__ float sb[256];
    const int tid = threadIdx.x;
    float m = -1e30f;
    for (int i = tid; i < BB; i += 256) m = fmaxf(m, s2[i]);
    sb[tid] = m; __syncthreads();
    for (int s = 128; s > 0; s >>= 1) { if (tid < s) sb[tid] = fmaxf(sb[tid], sb[tid + s]); __syncthreads(); }
    m = sb[0]; __syncthreads();
    float sum = 0.f;
    for (int i = tid; i < BB; i += 256) sum += __expf(s2[i] - m);
    sb[tid] = sum; __syncthreads();
    for (int s = 128; s > 0; s >>= 1) { if (tid < s) sb[tid] += sb[tid + s]; __syncthreads(); }
    if (tid == 0) { red[0] = m; red[1] = sb[0]; }
}

// ---------------- K2b: partial[b][k] = sum_{j in block} exp(s2[j]-m) * t[j][k] ----------------
__global__ __launch_bounds__(256) void k2b_colsum(
    const float* __restrict__ t, const float* __restrict__ s2,
    const float* __restrict__ red, float* __restrict__ partial)
{
    __shared__ float ew[128];
    __shared__ float sb[256];
    const int tid = threadIdx.x;
    const int rbase = blockIdx.x * 128;
    const float m = red[0];
    if (tid < 128) ew[tid] = __expf(s2[rbase + tid] - m);
    __syncthreads();
    const int col = tid & 127, half = tid >> 7;
    float acc = 0.f;
    for (int j = half; j < 128; j += 2)
        acc += ew[j] * t[(rbase + j) * 128 + col];
    sb[tid] = acc; __syncthreads();
    if (tid < 128) partial[blockIdx.x * 128 + tid] = sb[tid] + sb[tid + 128];
}

// ---------------- K2c: sent -> ap -> LN2 -> t2 -> r = sin(t2) ----------------
__global__ __launch_bounds__(128) void k2c_finish(
    const float* __restrict__ partial, const float* __restrict__ red,
    const float* __restrict__ anchors, const float* __restrict__ g2,
    const float* __restrict__ b2, const float* __restrict__ recvW,
    float* __restrict__ r_out)
{
    __shared__ float sent[128];
    __shared__ float na_s[128];
    __shared__ float sb[128];
    const int tid = threadIdx.x;
    const float S = red[1];
    float acc = 0.f;
    for (int b = 0; b < 32; ++b) acc += partial[b * 128 + tid];
    sent[tid] = acc / S;
    __syncthreads();
    float ap = 0.f;
    for (int c = 0; c < 128; ++c) ap += sent[c] * anchors[tid * 128 + c];
    sb[tid] = ap; __syncthreads();
    for (int s = 64; s > 0; s >>= 1) { if (tid < s) sb[tid] += sb[tid + s]; __syncthreads(); }
    const float mean = sb[0] * (1.0f / 128.0f); __syncthreads();
    const float dv = ap - mean;
    sb[tid] = dv * dv; __syncthreads();
    for (int s = 64; s > 0; s >>= 1) { if (tid < s) sb[tid] += sb[tid + s]; __syncthreads(); }
    const float var = sb[0] * (1.0f / 128.0f);
    const float rs = rsqrtf(var + 1e-5f);
    na_s[tid] = dv * rs * g2[tid] + b2[tid];
    __syncthreads();
    float t2 = 0.f;
    for (int k = 0; k < 128; ++k) t2 += na_s[k] * recvW[k * 128 + tid];
    r_out[tid] = sinf(t2);     // rec row == t2 row (uniform softmax over identical rows)
}

// ---------------- K3: ue = u + r (f32 + bf16 copy), pos gather ----------------
__global__ __launch_bounds__(256) void k3_ue_pos(
    const int* __restrict__ uidx, const float* __restrict__ utab,
    const int* __restrict__ pidx, const float* __restrict__ itab,
    const float* __restrict__ r, float* __restrict__ ue_out,
    float* __restrict__ pos_out, unsigned short* __restrict__ uebf)
{
    const int gid = blockIdx.x * 256 + threadIdx.x;    // 0 .. 524287
    const int i = gid >> 7, d = gid & 127;
    const float rv = r[d];
    const float u = utab[(long)uidx[i] * 128 + d];
    const float ue = u + rv;
    ue_out[gid] = ue;
    uebf[gid] = f2bf(ue);
    pos_out[gid] = itab[(long)pidx[i] * 128 + d];
}

// ---------------- K3b: item_table -> bf16 ----------------
__global__ __launch_bounds__(256) void k3b_cvt_item(
    const float* __restrict__ itab, unsigned short* __restrict__ ibf)
{
    const int gid = blockIdx.x * 256 + threadIdx.x;    // 0 .. 1,599,999 (x4 elems)
    const fl4_t v = *(const fl4_t*)(itab + (long)gid * 4);
    us4_t o;
    o.x = f2bf(v.x); o.y = f2bf(v.y); o.z = f2bf(v.z); o.w = f2bf(v.w);
    *(us4_t*)(ibf + (long)gid * 4) = o;
}

// ---------------- K4: preds = ue @ item^T   (bf16 MFMA, f32 out) ----------------
// BM=64 (4 waves x 16 rows), BN=256 (16 n-frags), K=128 (4 mfma k-steps)
__global__ __launch_bounds__(256) void k4_gemm(
    const unsigned short* __restrict__ uebf,
    const unsigned short* __restrict__ ibf,
    float* __restrict__ preds)
{
    const int tid = threadIdx.x;
    const int wave = tid >> 6, lane = tid & 63;
    const int l15 = lane & 15, kg = lane >> 4;     // kg in 0..3
    const int kb = kg * 8;

    const int rowA = blockIdx.x * 64 + wave * 16 + l15;
    bf8_t a[4];
    #pragma unroll
    for (int kk = 0; kk < 4; ++kk)
        a[kk] = *(const bf8_t*)(uebf + rowA * 128 + kk * 32 + kb);

    const int nbase = blockIdx.y * 256 + l15;
    f4_t acc[16];
    #pragma unroll
    for (int f = 0; f < 16; ++f) acc[f] = (f4_t){0.f, 0.f, 0.f, 0.f};

    #pragma unroll
    for (int f = 0; f < 16; ++f) {
        int col = nbase + f * 16;
        int colc = col < NII ? col : (NII - 1);        // clamp OOB loads; store is predicated
        const unsigned short* bp = ibf + colc * 128 + kb;
        #pragma unroll
        for (int kk = 0; kk < 4; ++kk) {
            bf8_t b = *(const bf8_t*)(bp + kk * 32);
            acc[f] = __builtin_amdgcn_mfma_f32_16x16x32_bf16(a[kk], b, acc[f], 0, 0, 0);
        }
    }

    const int rbase = blockIdx.x * 64 + wave * 16 + kg * 4;   // C: row=(lane>>4)*4+reg, col=lane&15
    const int cb = blockIdx.y * 256 + l15;
    #pragma unroll
    for (int f = 0; f < 16; ++f) {
        const int col = cb + f * 16;
        if (col < NII) {
            #pragma unroll
            for (int j = 0; j < 4; ++j)
                preds[(long)(rbase + j) * NII + col] = acc[f][j];
        }
    }
}

extern "C" void kernel_launch(void* const* d_in, const int* in_sizes, int n_in,
                              void* d_out, int out_size, void* d_ws, size_t ws_size,
                              hipStream_t stream) {
    const int*   uidx   = (const int*)  d_in[0];
    const int*   pidx   = (const int*)  d_in[1];
    const float* utab   = (const float*)d_in[2];
    const float* itab   = (const float*)d_in[3];
    const float* g1     = (const float*)d_in[4];
    const float* b1     = (const float*)d_in[5];
    const float* sendW  = (const float*)d_in[6];
    const float* senda  = (const float*)d_in[7];
    const float* anchors= (const float*)d_in[8];
    const float* g2     = (const float*)d_in[9];
    const float* b2     = (const float*)d_in[10];
    const float* recvW  = (const float*)d_in[11];
    // d_in[12] (recv_a) provably unused: second fca's softmax weights are exactly uniform.

    char* ws = (char*)d_ws;
    float* t_ws    = (float*)(ws + 0);              // 4096*128*4 = 2,097,152
    float* s2_ws   = (float*)(ws + 2097152);        // 16,384
    float* red_ws  = (float*)(ws + 2113536);        // 64 (m, S)
    float* part_ws = (float*)(ws + 2113600);        // 32*128*4 = 16,384
    float* r_ws    = (float*)(ws + 2129984);        // 512
    unsigned short* uebf = (unsigned short*)(ws + 2130496);   // 1,048,576
    unsigned short* ibf  = (unsigned short*)(ws + 3179072);   // 12,800,000 -> ends ~15.98 MB

    float* preds   = (float*)d_out;
    float* ue_out  = preds + (long)BB * NII;
    float* pos_out = ue_out + BB * DD;

    k3b_cvt_item<<<6250, 256, 0, stream>>>(itab, ibf);
    k1_embed_send<<<4096, 128, 0, stream>>>(uidx, utab, g1, b1, sendW, senda, t_ws, s2_ws);
    k2a_stats<<<1, 256, 0, stream>>>(s2_ws, red_ws);
    k2b_colsum<<<32, 256, 0, stream>>>(t_ws, s2_ws, red_ws, part_ws);
    k2c_finish<<<1, 128, 0, stream>>>(part_ws, red_ws, anchors, g2, b2, recvW, r_ws);
    k3_ue_pos<<<2048, 256, 0, stream>>>(uidx, utab, pidx, itab, r_ws, ue_out, pos_out, uebf);
    k4_gemm<<<dim3(64, 196, 1), 256, 0, stream>>>(uebf, ibf, preds);
}

// Round 2
// 305.248 us; speedup vs baseline: 1.7157x; 1.7157x over previous
//
#include <hip/hip_runtime.h>
#include <hip/hip_bf16.h>

#define BB   4096
#define DD   128
#define NII  50000

typedef __attribute__((ext_vector_type(8))) short  bf8_t;   // 8 bf16 in 4 VGPRs
typedef __attribute__((ext_vector_type(4))) float  f4_t;
typedef __attribute__((ext_vector_type(4))) unsigned short us4_t;
typedef __attribute__((ext_vector_type(4))) float  fl4_t;

static __device__ __forceinline__ unsigned short f2bf(float f) {
    unsigned u = __float_as_uint(f);
    u += 0x7fffu + ((u >> 16) & 1u);       // round-to-nearest-even
    return (unsigned short)(u >> 16);
}

static __device__ __forceinline__ void gload_lds16(const void* g, void* lds) {
    __builtin_amdgcn_global_load_lds(
        (const __attribute__((address_space(1))) void*)g,
        (__attribute__((address_space(3))) void*)lds, 16, 0, 0);
}

// ---------------- K1: gather + LN1 + t = nf @ send_W, s2 = t . a2 ----------------
__global__ __launch_bounds__(128) void k1_embed_send(
    const int* __restrict__ uidx, const float* __restrict__ utab,
    const float* __restrict__ g1, const float* __restrict__ b1,
    const float* __restrict__ sendW, const float* __restrict__ senda,
    float* __restrict__ t_out, float* __restrict__ s2_out)
{
    __shared__ float sb[128];
    __shared__ float nf[128];
    const int row = blockIdx.x;
    const int tid = threadIdx.x;
    const long urow = uidx[row];
    const float x = utab[urow * 128 + tid];

    sb[tid] = x; __syncthreads();
    for (int s = 64; s > 0; s >>= 1) { if (tid < s) sb[tid] += sb[tid + s]; __syncthreads(); }
    const float mean = sb[0] * (1.0f / 128.0f); __syncthreads();
    const float dv = x - mean;
    sb[tid] = dv * dv; __syncthreads();
    for (int s = 64; s > 0; s >>= 1) { if (tid < s) sb[tid] += sb[tid + s]; __syncthreads(); }
    const float var = sb[0] * (1.0f / 128.0f);
    const float rs = rsqrtf(var + 1e-5f);
    nf[tid] = dv * rs * g1[tid] + b1[tid];
    __syncthreads();

    float acc = 0.f;
    #pragma unroll 8
    for (int d = 0; d < 128; ++d) acc += nf[d] * sendW[d * 128 + tid];
    t_out[row * 128 + tid] = acc;

    const float p = acc * senda[128 + tid];   // a2 = send_a[128:]
    __syncthreads();
    sb[tid] = p; __syncthreads();
    for (int s = 64; s > 0; s >>= 1) { if (tid < s) sb[tid] += sb[tid + s]; __syncthreads(); }
    if (tid == 0) s2_out[row] = sb[0];
}

// ---------------- K2a: m = max(s2), S = sum exp(s2-m) ----------------
__global__ __launch_bounds__(256) void k2a_stats(
    const float* __restrict__ s2, float* __restrict__ red)
{
    __shared__ float sb[256];
    const int tid = threadIdx.x;
    float m = -1e30f;
    for (int i = tid; i < BB; i += 256) m = fmaxf(m, s2[i]);
    sb[tid] = m; __syncthreads();
    for (int s = 128; s > 0; s >>= 1) { if (tid < s) sb[tid] = fmaxf(sb[tid], sb[tid + s]); __syncthreads(); }
    m = sb[0]; __syncthreads();
    float sum = 0.f;
    for (int i = tid; i < BB; i += 256) sum += __expf(s2[i] - m);
    sb[tid] = sum; __syncthreads();
    for (int s = 128; s > 0; s >>= 1) { if (tid < s) sb[tid] += sb[tid + s]; __syncthreads(); }
    if (tid == 0) { red[0] = m; red[1] = sb[0]; }
}

// ---------------- K2b: partial[b][k] = sum_{j in block} exp(s2[j]-m) * t[j][k] ----------------
__global__ __launch_bounds__(256) void k2b_colsum(
    const float* __restrict__ t, const float* __restrict__ s2,
    const float* __restrict__ red, float* __restrict__ partial)
{
    __shared__ float ew[128];
    __shared__ float sb[256];
    const int tid = threadIdx.x;
    const int rbase = blockIdx.x * 128;
    const float m = red[0];
    if (tid < 128) ew[tid] = __expf(s2[rbase + tid] - m);
    __syncthreads();
    const int col = tid & 127, half = tid >> 7;
    float acc = 0.f;
    for (int j = half; j < 128; j += 2)
        acc += ew[j] * t[(rbase + j) * 128 + col];
    sb[tid] = acc; __syncthreads();
    if (tid < 128) partial[blockIdx.x * 128 + tid] = sb[tid] + sb[tid + 128];
}

// ---------------- K2c: sent -> ap -> LN2 -> t2 -> r = sin(t2) ----------------
__global__ __launch_bounds__(128) void k2c_finish(
    const float* __restrict__ partial, const float* __restrict__ red,
    const float* __restrict__ anchors, const float* __restrict__ g2,
    const float* __restrict__ b2, const float* __restrict__ recvW,
    float* __restrict__ r_out)
{
    __shared__ float sent[128];
    __shared__ float na_s[128];
    __shared__ float sb[128];
    const int tid = threadIdx.x;
    const float S = red[1];
    float acc = 0.f;
    for (int b = 0; b < 32; ++b) acc += partial[b * 128 + tid];
    sent[tid] = acc / S;
    __syncthreads();
    float ap = 0.f;
    for (int c = 0; c < 128; ++c) ap += sent[c] * anchors[tid * 128 + c];
    sb[tid] = ap; __syncthreads();
    for (int s = 64; s > 0; s >>= 1) { if (tid < s) sb[tid] += sb[tid + s]; __syncthreads(); }
    const float mean = sb[0] * (1.0f / 128.0f); __syncthreads();
    const float dv = ap - mean;
    sb[tid] = dv * dv; __syncthreads();
    for (int s = 64; s > 0; s >>= 1) { if (tid < s) sb[tid] += sb[tid + s]; __syncthreads(); }
    const float var = sb[0] * (1.0f / 128.0f);
    const float rs = rsqrtf(var + 1e-5f);
    na_s[tid] = dv * rs * g2[tid] + b2[tid];
    __syncthreads();
    float t2 = 0.f;
    for (int k = 0; k < 128; ++k) t2 += na_s[k] * recvW[k * 128 + tid];
    r_out[tid] = sinf(t2);     // rec row == t2 row (uniform softmax over identical rows)
}

// ---------------- K3: ue = u + r (f32 + bf16 copy), pos gather ----------------
__global__ __launch_bounds__(256) void k3_ue_pos(
    const int* __restrict__ uidx, const float* __restrict__ utab,
    const int* __restrict__ pidx, const float* __restrict__ itab,
    const float* __restrict__ r, float* __restrict__ ue_out,
    float* __restrict__ pos_out, unsigned short* __restrict__ uebf)
{
    const int gid = blockIdx.x * 256 + threadIdx.x;    // 0 .. 524287
    const int i = gid >> 7, d = gid & 127;
    const float rv = r[d];
    const float u = utab[(long)uidx[i] * 128 + d];
    const float ue = u + rv;
    ue_out[gid] = ue;
    uebf[gid] = f2bf(ue);
    pos_out[gid] = itab[(long)pidx[i] * 128 + d];
}

// ---------------- K3b: item_table -> bf16 ----------------
__global__ __launch_bounds__(256) void k3b_cvt_item(
    const float* __restrict__ itab, unsigned short* __restrict__ ibf)
{
    const int gid = blockIdx.x * 256 + threadIdx.x;    // 0 .. 1,599,999 (x4 elems)
    const fl4_t v = *(const fl4_t*)(itab + (long)gid * 4);
    us4_t o;
    o.x = f2bf(v.x); o.y = f2bf(v.y); o.z = f2bf(v.z); o.w = f2bf(v.w);
    *(us4_t*)(ibf + (long)gid * 4) = o;
}

// ---------------- K4 v2: preds = ue @ item^T  (128x128 tile, LDS-staged, XOR-swizzled) ----------------
// 256 thr = 4 waves (2x2), K=128 one-shot (4 mfma k-steps), per-wave 4x4 16x16 frags.
// LDS layout: [row][chunk] where chunk = 16B; physical chunk p of row r holds logical
// chunk p ^ (r&15)  -> ds_read_b128 across 16 rows hits 16 distinct chunks (2-way bank alias = free).
// Staging: global_load_lds dest is linear (wave base + lane*16); swizzle applied on the
// per-lane GLOBAL source address (m173 pattern).
__global__ __launch_bounds__(256) void k4_gemm(
    const unsigned short* __restrict__ uebf,
    const unsigned short* __restrict__ ibf,
    float* __restrict__ preds)
{
    __shared__ unsigned short lA[128 * 128];   // 32 KB
    __shared__ unsigned short lB[128 * 128];   // 32 KB

    const int tid = threadIdx.x;
    const int wave = tid >> 6, lane = tid & 63;
    const int l15 = lane & 15, kg = lane >> 4;       // kg 0..3
    const int row0 = blockIdx.x * 128;               // M tile base
    const int col0 = blockIdx.y * 128;               // N tile base

    // ---- stage A and B tiles (32 KB each): 8 instr each, 4 KB per instr (256 thr x 16B)
    #pragma unroll
    for (int i = 0; i < 8; ++i) {
        const int o   = (i * 256 + tid) * 16;        // linear LDS byte offset this lane fills
        const int r   = o >> 8;                      // tile-local row (256 B rows)
        const int ch  = (o >> 4) & 15;               // physical chunk
        const int sw  = ch ^ (r & 15);               // logical chunk to fetch
        // A: rows row0+r (always < 4096)
        gload_lds16(uebf + (size_t)(row0 + r) * 128 + sw * 8,
                    (char*)lA + i * 4096 + wave * 1024);
        // B: cols col0+r, clamp tail (garbage cols never stored)
        const int bc = (col0 + r) < NII ? (col0 + r) : (NII - 1);
        gload_lds16(ibf + (size_t)bc * 128 + sw * 8,
                    (char*)lB + i * 4096 + wave * 1024);
    }
    __syncthreads();

    const int wr = wave >> 1, wc = wave & 1;         // 2x2 wave grid, 64x64 per wave

    f4_t acc[4][4];
    #pragma unroll
    for (int m = 0; m < 4; ++m)
        #pragma unroll
        for (int n = 0; n < 4; ++n) acc[m][n] = (f4_t){0.f, 0.f, 0.f, 0.f};

    #pragma unroll
    for (int kk = 0; kk < 4; ++kk) {                 // K step of 32
        const int c = kk * 4 + kg;                   // logical 16B chunk within row
        bf8_t a[4], b[4];
        #pragma unroll
        for (int m = 0; m < 4; ++m) {
            const int r = wr * 64 + m * 16 + l15;
            a[m] = *(const bf8_t*)((const char*)lA + r * 256 + (c ^ (r & 15)) * 16);
        }
        #pragma unroll
        for (int n = 0; n < 4; ++n) {
            const int r = wc * 64 + n * 16 + l15;
            b[n] = *(const bf8_t*)((const char*)lB + r * 256 + (c ^ (r & 15)) * 16);
        }
        #pragma unroll
        for (int m = 0; m < 4; ++m)
            #pragma unroll
            for (int n = 0; n < 4; ++n)
                acc[m][n] = __builtin_amdgcn_mfma_f32_16x16x32_bf16(a[m], b[n], acc[m][n], 0, 0, 0);
    }

    // ---- store: C row = (kg*4 + j), col = l15 within each 16x16 frag
    const int orow = row0 + wr * 64 + kg * 4;
    const int ocol = col0 + wc * 64 + l15;
    #pragma unroll
    for (int m = 0; m < 4; ++m) {
        #pragma unroll
        for (int n = 0; n < 4; ++n) {
            const int col = ocol + n * 16;
            if (col < NII) {
                #pragma unroll
                for (int j = 0; j < 4; ++j)
                    preds[(long)(orow + m * 16 + j) * NII + col] = acc[m][n][j];
            }
        }
    }
}

extern "C" void kernel_launch(void* const* d_in, const int* in_sizes, int n_in,
                              void* d_out, int out_size, void* d_ws, size_t ws_size,
                              hipStream_t stream) {
    const int*   uidx   = (const int*)  d_in[0];
    const int*   pidx   = (const int*)  d_in[1];
    const float* utab   = (const float*)d_in[2];
    const float* itab   = (const float*)d_in[3];
    const float* g1     = (const float*)d_in[4];
    const float* b1     = (const float*)d_in[5];
    const float* sendW  = (const float*)d_in[6];
    const float* senda  = (const float*)d_in[7];
    const float* anchors= (const float*)d_in[8];
    const float* g2     = (const float*)d_in[9];
    const float* b2     = (const float*)d_in[10];
    const float* recvW  = (const float*)d_in[11];
    // d_in[12] (recv_a) provably unused: second fca's softmax weights are exactly uniform.

    char* ws = (char*)d_ws;
    float* t_ws    = (float*)(ws + 0);              // 4096*128*4 = 2,097,152
    float* s2_ws   = (float*)(ws + 2097152);        // 16,384
    float* red_ws  = (float*)(ws + 2113536);        // 64 (m, S)
    float* part_ws = (float*)(ws + 2113600);        // 32*128*4 = 16,384
    float* r_ws    = (float*)(ws + 2129984);        // 512
    unsigned short* uebf = (unsigned short*)(ws + 2130496);   // 1,048,576
    unsigned short* ibf  = (unsigned short*)(ws + 3179072);   // 12,800,000 -> ends ~15.98 MB

    float* preds   = (float*)d_out;
    float* ue_out  = preds + (long)BB * NII;
    float* pos_out = ue_out + BB * DD;

    k3b_cvt_item<<<6250, 256, 0, stream>>>(itab, ibf);
    k1_embed_send<<<4096, 128, 0, stream>>>(uidx, utab, g1, b1, sendW, senda, t_ws, s2_ws);
    k2a_stats<<<1, 256, 0, stream>>>(s2_ws, red_ws);
    k2b_colsum<<<32, 256, 0, stream>>>(t_ws, s2_ws, red_ws, part_ws);
    k2c_finish<<<1, 128, 0, stream>>>(part_ws, red_ws, anchors, g2, b2, recvW, r_ws);
    k3_ue_pos<<<2048, 256, 0, stream>>>(uidx, utab, pidx, itab, r_ws, ue_out, pos_out, uebf);
    k4_gemm<<<dim3(32, 391, 1), 256, 0, stream>>>(uebf, ibf, preds);
}

// Round 3
// 285.552 us; speedup vs baseline: 1.8341x; 1.0690x over previous
//
#include <hip/hip_runtime.h>
#include <hip/hip_bf16.h>

#define BB   4096
#define DD   128
#define NII  50000

typedef __attribute__((ext_vector_type(8))) short  bf8_t;   // 8 bf16 in 4 VGPRs
typedef __attribute__((ext_vector_type(4))) float  f4_t;
typedef __attribute__((ext_vector_type(4))) unsigned short us4_t;
typedef __attribute__((ext_vector_type(4))) float  fl4_t;

static __device__ __forceinline__ unsigned short f2bf(float f) {
    unsigned u = __float_as_uint(f);
    u += 0x7fffu + ((u >> 16) & 1u);       // round-to-nearest-even
    return (unsigned short)(u >> 16);
}

static __device__ __forceinline__ void gload_lds16(const void* g, void* lds) {
    __builtin_amdgcn_global_load_lds(
        (const __attribute__((address_space(1))) void*)g,
        (__attribute__((address_space(3))) void*)lds, 16, 0, 0);
}

// ---------------- K1: gather + LN1 + t = nf @ send_W, s2 = t . a2 ----------------
__global__ __launch_bounds__(128) void k1_embed_send(
    const int* __restrict__ uidx, const float* __restrict__ utab,
    const float* __restrict__ g1, const float* __restrict__ b1,
    const float* __restrict__ sendW, const float* __restrict__ senda,
    float* __restrict__ t_out, float* __restrict__ s2_out)
{
    __shared__ float sb[128];
    __shared__ float nf[128];
    const int row = blockIdx.x;
    const int tid = threadIdx.x;
    const long urow = uidx[row];
    const float x = utab[urow * 128 + tid];

    sb[tid] = x; __syncthreads();
    for (int s = 64; s > 0; s >>= 1) { if (tid < s) sb[tid] += sb[tid + s]; __syncthreads(); }
    const float mean = sb[0] * (1.0f / 128.0f); __syncthreads();
    const float dv = x - mean;
    sb[tid] = dv * dv; __syncthreads();
    for (int s = 64; s > 0; s >>= 1) { if (tid < s) sb[tid] += sb[tid + s]; __syncthreads(); }
    const float var = sb[0] * (1.0f / 128.0f);
    const float rs = rsqrtf(var + 1e-5f);
    nf[tid] = dv * rs * g1[tid] + b1[tid];
    __syncthreads();

    float acc = 0.f;
    #pragma unroll 8
    for (int d = 0; d < 128; ++d) acc += nf[d] * sendW[d * 128 + tid];
    t_out[row * 128 + tid] = acc;

    const float p = acc * senda[128 + tid];   // a2 = send_a[128:]
    __syncthreads();
    sb[tid] = p; __syncthreads();
    for (int s = 64; s > 0; s >>= 1) { if (tid < s) sb[tid] += sb[tid + s]; __syncthreads(); }
    if (tid == 0) s2_out[row] = sb[0];
}

// ---------------- K2b: stats (recomputed per block) + weighted column partial sums ----------------
__global__ __launch_bounds__(256) void k2b_colsum(
    const float* __restrict__ t, const float* __restrict__ s2,
    float* __restrict__ partial)
{
    __shared__ float ew[128];
    __shared__ float sb[256];
    const int tid = threadIdx.x;

    // recompute m = max(s2) locally (16 reads/thread, L2-resident)
    float m = -1e30f;
    for (int i = tid; i < BB; i += 256) m = fmaxf(m, s2[i]);
    sb[tid] = m; __syncthreads();
    for (int s = 128; s > 0; s >>= 1) { if (tid < s) sb[tid] = fmaxf(sb[tid], sb[tid + s]); __syncthreads(); }
    m = sb[0]; __syncthreads();

    const int rbase = blockIdx.x * 128;
    if (tid < 128) ew[tid] = __expf(s2[rbase + tid] - m);
    __syncthreads();
    const int col = tid & 127, half = tid >> 7;
    float acc = 0.f;
    for (int j = half; j < 128; j += 2)
        acc += ew[j] * t[(rbase + j) * 128 + col];
    sb[tid] = acc; __syncthreads();
    if (tid < 128) partial[blockIdx.x * 128 + tid] = sb[tid] + sb[tid + 128];
}

// ---------------- K2c: stats + sent -> ap -> LN2 -> t2 -> r = sin(t2) ----------------
__global__ __launch_bounds__(128) void k2c_finish(
    const float* __restrict__ partial, const float* __restrict__ s2,
    const float* __restrict__ anchors, const float* __restrict__ g2,
    const float* __restrict__ b2, const float* __restrict__ recvW,
    float* __restrict__ r_out)
{
    __shared__ float sent[128];
    __shared__ float na_s[128];
    __shared__ float sb[128];
    const int tid = threadIdx.x;

    // recompute m and S = sum exp(s2-m)  (32 reads/thread, L2-resident)
    float m = -1e30f;
    for (int i = tid; i < BB; i += 128) m = fmaxf(m, s2[i]);
    sb[tid] = m; __syncthreads();
    for (int s = 64; s > 0; s >>= 1) { if (tid < s) sb[tid] = fmaxf(sb[tid], sb[tid + s]); __syncthreads(); }
    m = sb[0]; __syncthreads();
    float sum = 0.f;
    for (int i = tid; i < BB; i += 128) sum += __expf(s2[i] - m);
    sb[tid] = sum; __syncthreads();
    for (int s = 64; s > 0; s >>= 1) { if (tid < s) sb[tid] += sb[tid + s]; __syncthreads(); }
    const float S = sb[0]; __syncthreads();

    float acc = 0.f;
    for (int b = 0; b < 32; ++b) acc += partial[b * 128 + tid];
    sent[tid] = acc / S;
    __syncthreads();
    float ap = 0.f;
    for (int c = 0; c < 128; ++c) ap += sent[c] * anchors[tid * 128 + c];
    sb[tid] = ap; __syncthreads();
    for (int s = 64; s > 0; s >>= 1) { if (tid < s) sb[tid] += sb[tid + s]; __syncthreads(); }
    const float mean = sb[0] * (1.0f / 128.0f); __syncthreads();
    const float dv = ap - mean;
    sb[tid] = dv * dv; __syncthreads();
    for (int s = 64; s > 0; s >>= 1) { if (tid < s) sb[tid] += sb[tid + s]; __syncthreads(); }
    const float var = sb[0] * (1.0f / 128.0f);
    const float rs = rsqrtf(var + 1e-5f);
    na_s[tid] = dv * rs * g2[tid] + b2[tid];
    __syncthreads();
    float t2 = 0.f;
    for (int k = 0; k < 128; ++k) t2 += na_s[k] * recvW[k * 128 + tid];
    r_out[tid] = sinf(t2);     // rec row == t2 row (uniform softmax over identical rows)
}

// ---------------- K3: ue = u + r (f32 + bf16 copy), pos gather ----------------
__global__ __launch_bounds__(256) void k3_ue_pos(
    const int* __restrict__ uidx, const float* __restrict__ utab,
    const int* __restrict__ pidx, const float* __restrict__ itab,
    const float* __restrict__ r, float* __restrict__ ue_out,
    float* __restrict__ pos_out, unsigned short* __restrict__ uebf)
{
    const int gid = blockIdx.x * 256 + threadIdx.x;    // 0 .. 524287
    const int i = gid >> 7, d = gid & 127;
    const float rv = r[d];
    const float u = utab[(long)uidx[i] * 128 + d];
    const float ue = u + rv;
    ue_out[gid] = ue;
    uebf[gid] = f2bf(ue);
    pos_out[gid] = itab[(long)pidx[i] * 128 + d];
}

// ---------------- K3b: item_table -> bf16 ----------------
__global__ __launch_bounds__(256) void k3b_cvt_item(
    const float* __restrict__ itab, unsigned short* __restrict__ ibf)
{
    const int gid = blockIdx.x * 256 + threadIdx.x;    // 0 .. 1,599,999 (x4 elems)
    const fl4_t v = *(const fl4_t*)(itab + (long)gid * 4);
    us4_t o;
    o.x = f2bf(v.x); o.y = f2bf(v.y); o.z = f2bf(v.z); o.w = f2bf(v.w);
    *(us4_t*)(ibf + (long)gid * 4) = o;
}

// ---------------- K4 v3: preds = ue @ item^T ----------------
// Changes vs v2: (1) grid x = N-tile fastest -> concurrent blocks write long contiguous
// row-streams (HBM write locality); (2) B-only LDS (32 KB, XOR-swizzled), A fragments
// loaded per-k-step straight from global (1 MB, L1/L2-resident) -> 4 blocks/CU.
__global__ __launch_bounds__(256, 4) void k4_gemm(
    const unsigned short* __restrict__ uebf,
    const unsigned short* __restrict__ ibf,
    float* __restrict__ preds)
{
    __shared__ unsigned short lB[128 * 128];   // 32 KB

    const int tid = threadIdx.x;
    const int wave = tid >> 6, lane = tid & 63;
    const int l15 = lane & 15, kg = lane >> 4;       // kg 0..3
    const int col0 = blockIdx.x * 128;               // N tile (fastest-varying)
    const int row0 = blockIdx.y * 128;               // M tile

    // ---- stage B tile (32 KB): 8 instr, 4 KB per instr (256 thr x 16B), swizzled source
    #pragma unroll
    for (int i = 0; i < 8; ++i) {
        const int o   = (i * 256 + tid) * 16;        // linear LDS byte offset this lane fills
        const int r   = o >> 8;                      // tile-local col-row (256 B rows)
        const int ch  = (o >> 4) & 15;               // physical chunk
        const int sw  = ch ^ (r & 15);               // logical chunk to fetch
        const int bc  = (col0 + r) < NII ? (col0 + r) : (NII - 1);
        gload_lds16(ibf + (size_t)bc * 128 + sw * 8,
                    (char*)lB + i * 4096 + wave * 1024);
    }

    const int wr = wave >> 1, wc = wave & 1;         // 2x2 wave grid, 64x64 per wave

    f4_t acc[4][4];
    #pragma unroll
    for (int m = 0; m < 4; ++m)
        #pragma unroll
        for (int n = 0; n < 4; ++n) acc[m][n] = (f4_t){0.f, 0.f, 0.f, 0.f};

    __syncthreads();

    #pragma unroll
    for (int kk = 0; kk < 4; ++kk) {                 // K step of 32
        const int c = kk * 4 + kg;                   // logical 16B chunk within row
        bf8_t a[4], b[4];
        #pragma unroll
        for (int m = 0; m < 4; ++m) {
            const int r = row0 + wr * 64 + m * 16 + l15;
            a[m] = *(const bf8_t*)(uebf + (size_t)r * 128 + c * 8);
        }
        #pragma unroll
        for (int n = 0; n < 4; ++n) {
            const int r = wc * 64 + n * 16 + l15;
            b[n] = *(const bf8_t*)((const char*)lB + r * 256 + (c ^ (r & 15)) * 16);
        }
        #pragma unroll
        for (int m = 0; m < 4; ++m)
            #pragma unroll
            for (int n = 0; n < 4; ++n)
                acc[m][n] = __builtin_amdgcn_mfma_f32_16x16x32_bf16(a[m], b[n], acc[m][n], 0, 0, 0);
    }

    // ---- store: C row = (kg*4 + j), col = l15 within each 16x16 frag
    const int orow = row0 + wr * 64 + kg * 4;
    const int ocol = col0 + wc * 64 + l15;
    #pragma unroll
    for (int m = 0; m < 4; ++m) {
        #pragma unroll
        for (int n = 0; n < 4; ++n) {
            const int col = ocol + n * 16;
            if (col < NII) {
                #pragma unroll
                for (int j = 0; j < 4; ++j)
                    preds[(long)(orow + m * 16 + j) * NII + col] = acc[m][n][j];
            }
        }
    }
}

extern "C" void kernel_launch(void* const* d_in, const int* in_sizes, int n_in,
                              void* d_out, int out_size, void* d_ws, size_t ws_size,
                              hipStream_t stream) {
    const int*   uidx   = (const int*)  d_in[0];
    const int*   pidx   = (const int*)  d_in[1];
    const float* utab   = (const float*)d_in[2];
    const float* itab   = (const float*)d_in[3];
    const float* g1     = (const float*)d_in[4];
    const float* b1     = (const float*)d_in[5];
    const float* sendW  = (const float*)d_in[6];
    const float* senda  = (const float*)d_in[7];
    const float* anchors= (const float*)d_in[8];
    const float* g2     = (const float*)d_in[9];
    const float* b2     = (const float*)d_in[10];
    const float* recvW  = (const float*)d_in[11];
    // d_in[12] (recv_a) provably unused: second fca's softmax weights are exactly uniform.

    char* ws = (char*)d_ws;
    float* t_ws    = (float*)(ws + 0);              // 4096*128*4 = 2,097,152
    float* s2_ws   = (float*)(ws + 2097152);        // 16,384
    float* part_ws = (float*)(ws + 2113600);        // 32*128*4 = 16,384
    float* r_ws    = (float*)(ws + 2129984);        // 512
    unsigned short* uebf = (unsigned short*)(ws + 2130496);   // 1,048,576
    unsigned short* ibf  = (unsigned short*)(ws + 3179072);   // 12,800,000 -> ends ~15.98 MB

    float* preds   = (float*)d_out;
    float* ue_out  = preds + (long)BB * NII;
    float* pos_out = ue_out + BB * DD;

    k3b_cvt_item<<<6250, 256, 0, stream>>>(itab, ibf);
    k1_embed_send<<<4096, 128, 0, stream>>>(uidx, utab, g1, b1, sendW, senda, t_ws, s2_ws);
    k2b_colsum<<<32, 256, 0, stream>>>(t_ws, s2_ws, part_ws);
    k2c_finish<<<1, 128, 0, stream>>>(part_ws, s2_ws, anchors, g2, b2, recvW, r_ws);
    k3_ue_pos<<<2048, 256, 0, stream>>>(uidx, utab, pidx, itab, r_ws, ue_out, pos_out, uebf);
    k4_gemm<<<dim3(391, 32, 1), 256, 0, stream>>>(uebf, ibf, preds);
}

// Round 4
// 252.393 us; speedup vs baseline: 2.0750x; 1.1314x over previous
//
#include <hip/hip_runtime.h>
#include <hip/hip_bf16.h>

#define BB   4096
#define DD   128
#define NII  50000

typedef __attribute__((ext_vector_type(8))) short  bf8_t;   // 8 bf16 in 4 VGPRs
typedef __attribute__((ext_vector_type(4))) float  f4_t;
typedef __attribute__((ext_vector_type(4))) unsigned short us4_t;
typedef __attribute__((ext_vector_type(4))) float  fl4_t;

static __device__ __forceinline__ unsigned short f2bf(float f) {
    unsigned u = __float_as_uint(f);
    u += 0x7fffu + ((u >> 16) & 1u);       // round-to-nearest-even
    return (unsigned short)(u >> 16);
}

static __device__ __forceinline__ void gload_lds16(const void* g, void* lds) {
    __builtin_amdgcn_global_load_lds(
        (const __attribute__((address_space(1))) void*)g,
        (__attribute__((address_space(3))) void*)lds, 16, 0, 0);
}

// ---------------- K1: gather + LN1 + t = nf @ send_W, s2 = t . a2 ----------------
__global__ __launch_bounds__(128) void k1_embed_send(
    const int* __restrict__ uidx, const float* __restrict__ utab,
    const float* __restrict__ g1, const float* __restrict__ b1,
    const float* __restrict__ sendW, const float* __restrict__ senda,
    float* __restrict__ t_out, float* __restrict__ s2_out)
{
    __shared__ float sb[128];
    __shared__ float nf[128];
    const int row = blockIdx.x;
    const int tid = threadIdx.x;
    const long urow = uidx[row];
    const float x = utab[urow * 128 + tid];

    sb[tid] = x; __syncthreads();
    for (int s = 64; s > 0; s >>= 1) { if (tid < s) sb[tid] += sb[tid + s]; __syncthreads(); }
    const float mean = sb[0] * (1.0f / 128.0f); __syncthreads();
    const float dv = x - mean;
    sb[tid] = dv * dv; __syncthreads();
    for (int s = 64; s > 0; s >>= 1) { if (tid < s) sb[tid] += sb[tid + s]; __syncthreads(); }
    const float var = sb[0] * (1.0f / 128.0f);
    const float rs = rsqrtf(var + 1e-5f);
    nf[tid] = dv * rs * g1[tid] + b1[tid];
    __syncthreads();

    float acc = 0.f;
    #pragma unroll 8
    for (int d = 0; d < 128; ++d) acc += nf[d] * sendW[d * 128 + tid];
    t_out[row * 128 + tid] = acc;

    const float p = acc * senda[128 + tid];   // a2 = send_a[128:]
    __syncthreads();
    sb[tid] = p; __syncthreads();
    for (int s = 64; s > 0; s >>= 1) { if (tid < s) sb[tid] += sb[tid + s]; __syncthreads(); }
    if (tid == 0) s2_out[row] = sb[0];
}

// ---------------- K2b: stats (recomputed per block) + weighted column partial sums ----------------
__global__ __launch_bounds__(256) void k2b_colsum(
    const float* __restrict__ t, const float* __restrict__ s2,
    float* __restrict__ partial)
{
    __shared__ float ew[128];
    __shared__ float sb[256];
    const int tid = threadIdx.x;

    float m = -1e30f;
    for (int i = tid; i < BB; i += 256) m = fmaxf(m, s2[i]);
    sb[tid] = m; __syncthreads();
    for (int s = 128; s > 0; s >>= 1) { if (tid < s) sb[tid] = fmaxf(sb[tid], sb[tid + s]); __syncthreads(); }
    m = sb[0]; __syncthreads();

    const int rbase = blockIdx.x * 128;
    if (tid < 128) ew[tid] = __expf(s2[rbase + tid] - m);
    __syncthreads();
    const int col = tid & 127, half = tid >> 7;
    float acc = 0.f;
    for (int j = half; j < 128; j += 2)
        acc += ew[j] * t[(rbase + j) * 128 + col];
    sb[tid] = acc; __syncthreads();
    if (tid < 128) partial[blockIdx.x * 128 + tid] = sb[tid] + sb[tid + 128];
}

// ---------------- K2c: stats + sent -> ap -> LN2 -> t2 -> r = sin(t2) ----------------
__global__ __launch_bounds__(128) void k2c_finish(
    const float* __restrict__ partial, const float* __restrict__ s2,
    const float* __restrict__ anchors, const float* __restrict__ g2,
    const float* __restrict__ b2, const float* __restrict__ recvW,
    float* __restrict__ r_out)
{
    __shared__ float sent[128];
    __shared__ float na_s[128];
    __shared__ float sb[128];
    const int tid = threadIdx.x;

    float m = -1e30f;
    for (int i = tid; i < BB; i += 128) m = fmaxf(m, s2[i]);
    sb[tid] = m; __syncthreads();
    for (int s = 64; s > 0; s >>= 1) { if (tid < s) sb[tid] = fmaxf(sb[tid], sb[tid + s]); __syncthreads(); }
    m = sb[0]; __syncthreads();
    float sum = 0.f;
    for (int i = tid; i < BB; i += 128) sum += __expf(s2[i] - m);
    sb[tid] = sum; __syncthreads();
    for (int s = 64; s > 0; s >>= 1) { if (tid < s) sb[tid] += sb[tid + s]; __syncthreads(); }
    const float S = sb[0]; __syncthreads();

    float acc = 0.f;
    for (int b = 0; b < 32; ++b) acc += partial[b * 128 + tid];
    sent[tid] = acc / S;
    __syncthreads();
    float ap = 0.f;
    for (int c = 0; c < 128; ++c) ap += sent[c] * anchors[tid * 128 + c];
    sb[tid] = ap; __syncthreads();
    for (int s = 64; s > 0; s >>= 1) { if (tid < s) sb[tid] += sb[tid + s]; __syncthreads(); }
    const float mean = sb[0] * (1.0f / 128.0f); __syncthreads();
    const float dv = ap - mean;
    sb[tid] = dv * dv; __syncthreads();
    for (int s = 64; s > 0; s >>= 1) { if (tid < s) sb[tid] += sb[tid + s]; __syncthreads(); }
    const float var = sb[0] * (1.0f / 128.0f);
    const float rs = rsqrtf(var + 1e-5f);
    na_s[tid] = dv * rs * g2[tid] + b2[tid];
    __syncthreads();
    float t2 = 0.f;
    for (int k = 0; k < 128; ++k) t2 += na_s[k] * recvW[k * 128 + tid];
    r_out[tid] = sinf(t2);     // rec row == t2 row (uniform softmax over identical rows)
}

// ---------------- K3: ue = u + r (f32 + bf16 copy), pos gather ----------------
__global__ __launch_bounds__(256) void k3_ue_pos(
    const int* __restrict__ uidx, const float* __restrict__ utab,
    const int* __restrict__ pidx, const float* __restrict__ itab,
    const float* __restrict__ r, float* __restrict__ ue_out,
    float* __restrict__ pos_out, unsigned short* __restrict__ uebf)
{
    const int gid = blockIdx.x * 256 + threadIdx.x;    // 0 .. 524287
    const int i = gid >> 7, d = gid & 127;
    const float rv = r[d];
    const float u = utab[(long)uidx[i] * 128 + d];
    const float ue = u + rv;
    ue_out[gid] = ue;
    uebf[gid] = f2bf(ue);
    pos_out[gid] = itab[(long)pidx[i] * 128 + d];
}

// ---------------- K3b: item_table -> bf16 ----------------
__global__ __launch_bounds__(256) void k3b_cvt_item(
    const float* __restrict__ itab, unsigned short* __restrict__ ibf)
{
    const int gid = blockIdx.x * 256 + threadIdx.x;    // 0 .. 1,599,999 (x4 elems)
    const fl4_t v = *(const fl4_t*)(itab + (long)gid * 4);
    us4_t o;
    o.x = f2bf(v.x); o.y = f2bf(v.y); o.z = f2bf(v.z); o.w = f2bf(v.w);
    *(us4_t*)(ibf + (long)gid * 4) = o;
}

// ---------------- K4 v4: preds = ue @ item^T ----------------
// Both A and B staged in LDS (XOR-swizzled, gload_lds w=16). Epilogue transposes the
// column-major C fragments through a padded LDS slice (stride 76 words, 2 halves to fit
// 64 KB total) and stores preds as coalesced dwordx4. VMEM instrs/block: 352 -> 128.
__global__ __launch_bounds__(256, 2) void k4_gemm(
    const unsigned short* __restrict__ uebf,
    const unsigned short* __restrict__ ibf,
    float* __restrict__ preds)
{
    __shared__ char smem[65536];
    unsigned short* lA = (unsigned short*)smem;            // 32 KB
    unsigned short* lB = (unsigned short*)(smem + 32768);  // 32 KB

    const int tid = threadIdx.x;
    const int wave = tid >> 6, lane = tid & 63;
    const int l15 = lane & 15, kg = lane >> 4;       // kg 0..3
    const int col0 = blockIdx.x * 128;               // N tile (fastest-varying)
    const int row0 = blockIdx.y * 128;               // M tile

    // ---- stage A and B tiles (32 KB each): 8 gload_lds each per thread-iter
    #pragma unroll
    for (int i = 0; i < 8; ++i) {
        const int o   = (i * 256 + tid) * 16;        // linear LDS byte offset this lane fills
        const int r   = o >> 8;                      // tile-local row (256 B rows)
        const int ch  = (o >> 4) & 15;               // physical chunk
        const int sw  = ch ^ (r & 15);               // logical chunk to fetch
        gload_lds16(uebf + (size_t)(row0 + r) * 128 + sw * 8,
                    (char*)lA + i * 4096 + wave * 1024);
        const int bc  = (col0 + r) < NII ? (col0 + r) : (NII - 1);
        gload_lds16(ibf + (size_t)bc * 128 + sw * 8,
                    (char*)lB + i * 4096 + wave * 1024);
    }

    const int wr = wave >> 1, wc = wave & 1;         // 2x2 wave grid, 64x64 per wave

    f4_t acc[4][4];
    #pragma unroll
    for (int m = 0; m < 4; ++m)
        #pragma unroll
        for (int n = 0; n < 4; ++n) acc[m][n] = (f4_t){0.f, 0.f, 0.f, 0.f};

    __syncthreads();

    #pragma unroll
    for (int kk = 0; kk < 4; ++kk) {                 // K step of 32
        const int c = kk * 4 + kg;                   // logical 16B chunk within row
        bf8_t a[4], b[4];
        #pragma unroll
        for (int m = 0; m < 4; ++m) {
            const int r = wr * 64 + m * 16 + l15;
            a[m] = *(const bf8_t*)((const char*)lA + r * 256 + (c ^ (r & 15)) * 16);
        }
        #pragma unroll
        for (int n = 0; n < 4; ++n) {
            const int r = wc * 64 + n * 16 + l15;
            b[n] = *(const bf8_t*)((const char*)lB + r * 256 + (c ^ (r & 15)) * 16);
        }
        #pragma unroll
        for (int m = 0; m < 4; ++m)
            #pragma unroll
            for (int n = 0; n < 4; ++n)
                acc[m][n] = __builtin_amdgcn_mfma_f32_16x16x32_bf16(a[m], b[n], acc[m][n], 0, 0, 0);
    }

    // ---- epilogue: transpose through LDS (reuses smem; all frag reads drained by barrier)
    __syncthreads();
    float* ep = (float*)smem + wave * (32 * 76);     // per-wave 32x64 slice, stride 76 words

    #pragma unroll
    for (int h = 0; h < 2; ++h) {                    // two 32-row halves of the 64x64 wave tile
        #pragma unroll
        for (int mm = 0; mm < 2; ++mm) {
            const int m = h * 2 + mm;
            #pragma unroll
            for (int n = 0; n < 4; ++n)
                #pragma unroll
                for (int j = 0; j < 4; ++j)
                    ep[(mm * 16 + kg * 4 + j) * 76 + n * 16 + l15] = acc[m][n][j];
        }
        #pragma unroll
        for (int rr = 0; rr < 8; ++rr) {
            const int lrow = rr * 4 + (lane >> 4);                 // 0..31
            const f4_t v = *(const f4_t*)(ep + lrow * 76 + (lane & 15) * 4);
            const int grow = row0 + wr * 64 + h * 32 + lrow;
            const int gcol = col0 + wc * 64 + (lane & 15) * 4;     // 4-aligned; NII%4==0
            if (gcol < NII)
                *(fl4_t*)(preds + (long)grow * NII + gcol) = v;
        }
    }
}

extern "C" void kernel_launch(void* const* d_in, const int* in_sizes, int n_in,
                              void* d_out, int out_size, void* d_ws, size_t ws_size,
                              hipStream_t stream) {
    const int*   uidx   = (const int*)  d_in[0];
    const int*   pidx   = (const int*)  d_in[1];
    const float* utab   = (const float*)d_in[2];
    const float* itab   = (const float*)d_in[3];
    const float* g1     = (const float*)d_in[4];
    const float* b1     = (const float*)d_in[5];
    const float* sendW  = (const float*)d_in[6];
    const float* senda  = (const float*)d_in[7];
    const float* anchors= (const float*)d_in[8];
    const float* g2     = (const float*)d_in[9];
    const float* b2     = (const float*)d_in[10];
    const float* recvW  = (const float*)d_in[11];
    // d_in[12] (recv_a) provably unused: second fca's softmax weights are exactly uniform.

    char* ws = (char*)d_ws;
    float* t_ws    = (float*)(ws + 0);              // 4096*128*4 = 2,097,152
    float* s2_ws   = (float*)(ws + 2097152);        // 16,384
    float* part_ws = (float*)(ws + 2113600);        // 32*128*4 = 16,384
    float* r_ws    = (float*)(ws + 2129984);        // 512
    unsigned short* uebf = (unsigned short*)(ws + 2130496);   // 1,048,576
    unsigned short* ibf  = (unsigned short*)(ws + 3179072);   // 12,800,000 -> ends ~15.98 MB

    float* preds   = (float*)d_out;
    float* ue_out  = preds + (long)BB * NII;
    float* pos_out = ue_out + BB * DD;

    k3b_cvt_item<<<6250, 256, 0, stream>>>(itab, ibf);
    k1_embed_send<<<4096, 128, 0, stream>>>(uidx, utab, g1, b1, sendW, senda, t_ws, s2_ws);
    k2b_colsum<<<32, 256, 0, stream>>>(t_ws, s2_ws, part_ws);
    k2c_finish<<<1, 128, 0, stream>>>(part_ws, s2_ws, anchors, g2, b2, recvW, r_ws);
    k3_ue_pos<<<2048, 256, 0, stream>>>(uidx, utab, pidx, itab, r_ws, ue_out, pos_out, uebf);
    k4_gemm<<<dim3(391, 32, 1), 256, 0, stream>>>(uebf, ibf, preds);
}